// Round 7
// baseline (260.129 us; speedup 1.0000x reference)
//
#include <hip/hip_runtime.h>
#include <hip/hip_bf16.h>

// Problem constants (fixed by reference). ALL float tensors are float32;
// indices int32. MFMA runs on bf16-converted fragments; accumulate + epilogue
// in fp32.
#define NB     131072   // batch
#define NCH    16       // charts
#define NPAIR  256      // (src,tgt) pair buckets
#define LDW    136      // LDS weight-row stride in bf16 elems (16B-aligned rows)
#define LDH    136      // LDS h-row stride in bf16 elems
#define CAP    1024     // sorted-slice chunk capacity (bucket avg 512, max ~640)

// Workspace layout (ints): hist/cursor @0 (256) | off @256 (257) | sorted @528 (NB)
#define WS_HIST   0
#define WS_OFF    256
#define WS_SORTED 528
#define WS_BYTES  ((WS_SORTED + NB) * 4)   // 526,400

typedef short short8 __attribute__((ext_vector_type(8)));   // 8 x bf16 (4 VGPRs) MFMA frag
typedef short short4v __attribute__((ext_vector_type(4)));  // 4 x bf16 (8B, one ds_write_b64)
typedef float f32x4  __attribute__((ext_vector_type(4)));   // MFMA accumulator / fp32 vec

__device__ __forceinline__ short bfbits(float x) {
    union { __hip_bfloat16 h; short s; } u;
    u.h = __float2bfloat16(x);
    return u.s;
}

// Load 8 consecutive fp32 (32B, 16B-aligned) and convert to a bf16x8 MFMA frag.
__device__ __forceinline__ short8 cvt_frag(const float* __restrict__ p) {
    const f32x4 lo = *(const f32x4*)p;
    const f32x4 hi = *(const f32x4*)(p + 4);
    short8 r;
    r[0] = bfbits(lo[0]); r[1] = bfbits(lo[1]); r[2] = bfbits(lo[2]); r[3] = bfbits(lo[3]);
    r[4] = bfbits(hi[0]); r[5] = bfbits(hi[1]); r[6] = bfbits(hi[2]); r[7] = bfbits(hi[3]);
    return r;
}

// Pack two f32x4 into one bf16x8 MFMA frag.
__device__ __forceinline__ short8 pack_frag(f32x4 lo, f32x4 hi) {
    short8 r;
    r[0] = bfbits(lo[0]); r[1] = bfbits(lo[1]); r[2] = bfbits(lo[2]); r[3] = bfbits(lo[3]);
    r[4] = bfbits(hi[0]); r[5] = bfbits(hi[1]); r[6] = bfbits(hi[2]); r[7] = bfbits(hi[3]);
    return r;
}

// ---------------------------------------------------------------- k_init ----
__global__ void k_init(int* __restrict__ hist) {
    hist[threadIdx.x] = 0;
}

// ---------------------------------------------------------------- k_hist ----
__global__ __launch_bounds__(256) void k_hist(const int* __restrict__ si,
                                              const int* __restrict__ ti,
                                              int* __restrict__ hist) {
    __shared__ int sh[NPAIR];
    const int t = threadIdx.x;
    sh[t] = 0;
    __syncthreads();
    const int base = blockIdx.x * 1024 + t;
#pragma unroll
    for (int j = 0; j < 4; ++j) {
        const int i = base + j * 256;                       // coalesced
        const int k = (si[i] * NCH + ti[i]) & (NPAIR - 1);  // masked: never OOB
        atomicAdd(&sh[k], 1);
    }
    __syncthreads();
    if (sh[t]) atomicAdd(&hist[t], sh[t]);
}

// ---------------------------------------------------------------- k_scan ----
__global__ __launch_bounds__(256) void k_scan(int* __restrict__ hist,
                                              int* __restrict__ off) {
    __shared__ int s[NPAIR];
    const int t = threadIdx.x;
    const int v = hist[t];
    s[t] = v;
    __syncthreads();
#pragma unroll
    for (int d = 1; d < NPAIR; d <<= 1) {
        const int x = (t >= d) ? s[t - d] : 0;
        __syncthreads();
        s[t] += x;
        __syncthreads();
    }
    off[t + 1] = s[t];                 // inclusive -> off[1..256]
    if (t == 0) off[0] = 0;
    hist[t] = s[t] - v;                // exclusive prefix -> cursor start
}

// ------------------------------------------------------------- k_scatter ----
__global__ __launch_bounds__(256) void k_scatter(const int* __restrict__ si,
                                                 const int* __restrict__ ti,
                                                 int* __restrict__ cursor,
                                                 int* __restrict__ sorted) {
    __shared__ int sh[NPAIR];
    __shared__ int sbase[NPAIR];
    const int t = threadIdx.x;
    sh[t] = 0;
    __syncthreads();
    int key[4], rank[4];
    const int base = blockIdx.x * 1024 + t;
#pragma unroll
    for (int j = 0; j < 4; ++j) {
        const int i = base + j * 256;
        const int k = (si[i] * NCH + ti[i]) & (NPAIR - 1);
        key[j]  = k;
        rank[j] = atomicAdd(&sh[k], 1);
    }
    __syncthreads();
    sbase[t] = sh[t] ? atomicAdd(&cursor[t], sh[t]) : 0;
    __syncthreads();
#pragma unroll
    for (int j = 0; j < 4; ++j) {
        const int slot = sbase[key[j]] + rank[j];
        if (slot >= 0 && slot < NB)
            sorted[slot] = base + j * 256;
    }
}

// ---------------------------------------------------------------- k_gemm ----
// ROUND-4 STRUCTURE (proven best): one block per bucket, 512 threads =
// 8 waves, wave-autonomous zero-barrier main loop, 32-row groups (two
// 16-row halves share every B ds_read; dual acc chains), 1-group-ahead
// register prefetch of the z gather. Round-7 change: BOTH MFMAs take the
// WEIGHT as the A (first) operand. The C-layout (col=lane&15,
// row=(lane>>4)*4+reg) then puts 4 CONSECUTIVE output-dim elements in each
// lane's regs, so:
//   - h epilogue: one ds_write_b64 per nt (was 4 scalar ds_write_b16),
//   - C store: one global_store_dwordx4 per nt (was 4 scalar dwords),
// with biases applied as fp32 f32x4 (cbv/dbv indexed along the out-dim).
// All loads, LDS layouts, and the schedule are byte-identical to round 4.
// (Do NOT use cooperative launches here: round-6 measured ~+30us harness
// overhead. Do NOT shrink the 32-row group: round-5 measured 37->61us.)
__global__ __launch_bounds__(512, 2)
void k_gemm(const float* __restrict__ z,
            const float* __restrict__ encw,
            const float* __restrict__ decw,
            const float* __restrict__ cpar,
            const float* __restrict__ dpar,
            const int* __restrict__ off,
            const int* __restrict__ sorted,
            float* __restrict__ out) {
    __shared__ int sRowLds[CAP];
    __shared__ __align__(16) __hip_bfloat16 sW1[128 * LDW];
    __shared__ __align__(16) __hip_bfloat16 sW2[128 * LDW];
    __shared__ __align__(16) __hip_bfloat16 sH[8 * 32 * LDH];

    const int bucket = blockIdx.x;
    const int srcc = bucket >> 4;
    const int tgtc = bucket & (NCH - 1);
    const int beg = off[bucket];
    const int end = off[bucket + 1];

    const int tid  = threadIdx.x;
    const int lane = tid & 63;
    const int wv   = tid >> 6;
    const int lr   = lane & 15;
    const int lhi  = lane >> 4;

    {
        const float* W1 = encw + srcc * 16384;
        const float* W2 = decw + tgtc * 16384;
#pragma unroll
        for (int it = 0; it < 4; ++it) {
            const int f = (it * 512 + tid) * 8;
            const int row = f >> 7, col = f & 127;
            *(short8*)(sW1 + row * LDW + col) = cvt_frag(W1 + f);
            *(short8*)(sW2 + row * LDW + col) = cvt_frag(W2 + f);
        }
    }

    // biases along the OUTPUT dim of each GEMM (4 consecutive per lane)
    f32x4 cbv[8], dbv[8];
#pragma unroll
    for (int nt = 0; nt < 8; ++nt) {
        cbv[nt] = *(const f32x4*)(cpar + srcc * 128 + nt * 16 + lhi * 4);
        dbv[nt] = *(const f32x4*)(dpar + tgtc * 128 + nt * 16 + lhi * 4);
    }

    __hip_bfloat16* const hs = sH + wv * (32 * LDH);
    f32x4 bufA[8], bufB[8];

    auto pf = [&](int g) {
        const int r0 = sRowLds[(g << 5) + lr];
        const int r1 = sRowLds[(g << 5) + 16 + lr];
        const float* p0 = z + (long)(r0 < 0 ? 0 : r0) * 128 + lhi * 8;
        const float* p1 = z + (long)(r1 < 0 ? 0 : r1) * 128 + lhi * 8;
#pragma unroll
        for (int k = 0; k < 4; ++k) {
            bufA[2 * k]     = *(const f32x4*)(p0 + k * 32);
            bufA[2 * k + 1] = *(const f32x4*)(p0 + k * 32 + 4);
            bufB[2 * k]     = *(const f32x4*)(p1 + k * 32);
            bufB[2 * k + 1] = *(const f32x4*)(p1 + k * 32 + 4);
        }
    };

    for (int cb0 = beg; cb0 < end; cb0 += CAP) {
        const int cnt = min(end - cb0, CAP);
        __syncthreads();
        for (int i = tid; i < CAP; i += 512) {
            int v = (i < cnt) ? sorted[cb0 + i] : -1;
            sRowLds[i] = ((unsigned)v < (unsigned)NB) ? v : -1;
        }
        __syncthreads();

        const int ng = (cnt + 31) >> 5;
        int g = wv;
        if (g < ng) pf(g);
        while (g < ng) {
            short8 a0[4], a1[4];
#pragma unroll
            for (int k = 0; k < 4; ++k) {
                a0[k] = pack_frag(bufA[2 * k], bufA[2 * k + 1]);
                a1[k] = pack_frag(bufB[2 * k], bufB[2 * k + 1]);
            }
            const int gn = g + 8;
            if (gn < ng) pf(gn);

            // -------- GEMM1 (swapped): D[r][m] = W1 x z^T --------
            f32x4 acc0[8], acc1[8];
#pragma unroll
            for (int nt = 0; nt < 8; ++nt) { acc0[nt] = (f32x4)(0.0f); acc1[nt] = (f32x4)(0.0f); }

#pragma unroll
            for (int k = 0; k < 4; ++k) {
#pragma unroll
                for (int nt = 0; nt < 8; ++nt) {
                    const short8 b = *(const short8*)(sW1 + (nt * 16 + lr) * LDW + k * 32 + lhi * 8);
                    acc0[nt] = __builtin_amdgcn_mfma_f32_16x16x32_bf16(b, a0[k], acc0[nt], 0, 0, 0);
                    acc1[nt] = __builtin_amdgcn_mfma_f32_16x16x32_bf16(b, a1[k], acc1[nt], 0, 0, 0);
                }
            }

            // h (+ c bias): lane holds h[m=lr][r=nt*16+lhi*4+reg] -> one
            // ds_write_b64 per nt per half. Same-wave DS ops are in-order;
            // GEMM2's h reads are byte-identical to round 4.
#pragma unroll
            for (int nt = 0; nt < 8; ++nt) {
                const f32x4 h0 = acc0[nt] + cbv[nt];
                const f32x4 h1 = acc1[nt] + cbv[nt];
                short4v w0, w1;
#pragma unroll
                for (int r = 0; r < 4; ++r) { w0[r] = bfbits(h0[r]); w1[r] = bfbits(h1[r]); }
                *(short4v*)(hs + lr * LDH + nt * 16 + lhi * 4)        = w0;
                *(short4v*)(hs + (16 + lr) * LDH + nt * 16 + lhi * 4) = w1;
            }

            // -------- GEMM2 (swapped): D[e][m] = W2 x h^T --------
#pragma unroll
            for (int nt = 0; nt < 8; ++nt) { acc0[nt] = (f32x4)(0.0f); acc1[nt] = (f32x4)(0.0f); }

#pragma unroll
            for (int k = 0; k < 4; ++k) {
                const short8 ah0 = *(const short8*)(hs + lr * LDH + k * 32 + lhi * 8);
                const short8 ah1 = *(const short8*)(hs + (16 + lr) * LDH + k * 32 + lhi * 8);
#pragma unroll
                for (int nt = 0; nt < 8; ++nt) {
                    const short8 b = *(const short8*)(sW2 + (nt * 16 + lr) * LDW + k * 32 + lhi * 8);
                    acc0[nt] = __builtin_amdgcn_mfma_f32_16x16x32_bf16(b, ah0, acc0[nt], 0, 0, 0);
                    acc1[nt] = __builtin_amdgcn_mfma_f32_16x16x32_bf16(b, ah1, acc1[nt], 0, 0, 0);
                }
            }

            // store (+ d bias): lane holds out[e=nt*16+lhi*4+reg][m=lr]
            // -> one global_store_dwordx4 per nt per half (16B granules,
            // 4 lanes contiguous = same 64B segments as round 4).
            {
                const int grow0 = sRowLds[(g << 5) + lr];
                const int grow1 = sRowLds[(g << 5) + 16 + lr];
#pragma unroll
                for (int nt = 0; nt < 8; ++nt) {
                    if (grow0 >= 0)
                        *(f32x4*)(out + (long)grow0 * 128 + nt * 16 + lhi * 4) = acc0[nt] + dbv[nt];
                    if (grow1 >= 0)
                        *(f32x4*)(out + (long)grow1 * 128 + nt * 16 + lhi * 4) = acc1[nt] + dbv[nt];
                }
            }
            g = gn;
        }
    }
}

// ------------------------------------------------------------- k_fallback ---
// Zero-workspace correct path: one wave per row, fp32 VALU dot products.
__global__ __launch_bounds__(256)
void k_fallback(const float* __restrict__ z,
                const int* __restrict__ si, const int* __restrict__ ti,
                const float* __restrict__ ew,
                const float* __restrict__ dw,
                const float* __restrict__ cp,
                const float* __restrict__ dp,
                float* __restrict__ out) {
    __shared__ float sh[4][128];
    const int lane = threadIdx.x & 63, wv = threadIdx.x >> 6;
    for (int row = blockIdx.x * 4 + wv; row < NB; row += (int)gridDim.x * 4) {
        const int sc = si[row] & (NCH - 1), tc = ti[row] & (NCH - 1);
        const float* zr = z + (long)row * 128;
        const float* W1 = ew + sc * 16384;
        float h0 = cp[sc * 128 + lane];
        float h1 = cp[sc * 128 + lane + 64];
        for (int d = 0; d < 128; ++d) {
            const float zv = zr[d];
            h0 += zv * W1[lane * 128 + d];
            h1 += zv * W1[(lane + 64) * 128 + d];
        }
        sh[wv][lane] = h0;
        sh[wv][lane + 64] = h1;
        __syncthreads();
        const float* W2 = dw + tc * 16384;
        float o0 = dp[tc * 128 + lane];
        float o1 = dp[tc * 128 + lane + 64];
        for (int r = 0; r < 128; ++r) {
            const float hv = sh[wv][r];
            o0 += hv * W2[lane * 128 + r];
            o1 += hv * W2[(lane + 64) * 128 + r];
        }
        out[(long)row * 128 + lane] = o0;
        out[(long)row * 128 + lane + 64] = o1;
        __syncthreads();
    }
}

// ----------------------------------------------------------------- launch ---
extern "C" void kernel_launch(void* const* d_in, const int* in_sizes, int n_in,
                              void* d_out, int out_size, void* d_ws, size_t ws_size,
                              hipStream_t stream) {
    // Reference dtypes: all float tensors float32, indices int32, output float32.
    const float* z  = (const float*)d_in[0];
    const int*   si = (const int*)d_in[1];
    const int*   ti = (const int*)d_in[2];
    const float* ew = (const float*)d_in[3];
    const float* dw = (const float*)d_in[4];
    const float* cp = (const float*)d_in[5];
    const float* dp = (const float*)d_in[6];
    float* out = (float*)d_out;

    if (ws_size >= (size_t)WS_BYTES) {
        int* hist   = (int*)d_ws + WS_HIST;    // 256, becomes cursor after scan
        int* off    = (int*)d_ws + WS_OFF;     // 257
        int* sorted = (int*)d_ws + WS_SORTED;  // NB

        k_init<<<1, NPAIR, 0, stream>>>(hist);
        k_hist<<<128, 256, 0, stream>>>(si, ti, hist);
        k_scan<<<1, NPAIR, 0, stream>>>(hist, off);
        k_scatter<<<128, 256, 0, stream>>>(si, ti, hist, sorted);
        k_gemm<<<NPAIR, 512, 0, stream>>>(z, ew, dw, cp, dp, off, sorted, out);
    } else {
        k_fallback<<<1024, 256, 0, stream>>>(z, si, ti, ew, dw, cp, dp, out);
    }
}

// Round 8
// 146.297 us; speedup vs baseline: 1.7781x; 1.7781x over previous
//
#include <hip/hip_runtime.h>
#include <hip/hip_bf16.h>

// Problem constants (fixed by reference). ALL float tensors are float32;
// indices int32. MFMA runs on bf16-converted fragments; accumulate + epilogue
// in fp32.
#define NB     131072   // batch
#define NCH    16       // charts
#define NPAIR  256      // (src,tgt) pair buckets
#define LDW    136      // LDS weight-row stride in bf16 elems (16B-aligned rows)
#define LDH    136      // LDS h-row stride in bf16 elems
#define CAP    1024     // sorted-slice chunk capacity (bucket avg 512, max ~640)

// Workspace layout (ints): hist/cursor @0 (256) | off @256 (257) | sorted @528 (NB)
#define WS_HIST   0
#define WS_OFF    256
#define WS_SORTED 528
#define WS_BYTES  ((WS_SORTED + NB) * 4)   // 526,400

typedef short short8 __attribute__((ext_vector_type(8)));   // 8 x bf16 (4 VGPRs) MFMA frag
typedef float f32x4  __attribute__((ext_vector_type(4)));   // MFMA accumulator / fp32 vec

__device__ __forceinline__ short bfbits(float x) {
    union { __hip_bfloat16 h; short s; } u;
    u.h = __float2bfloat16(x);
    return u.s;
}

// Load 8 consecutive fp32 (32B, 16B-aligned) and convert to a bf16x8 MFMA frag.
__device__ __forceinline__ short8 cvt_frag(const float* __restrict__ p) {
    const f32x4 lo = *(const f32x4*)p;
    const f32x4 hi = *(const f32x4*)(p + 4);
    short8 r;
    r[0] = bfbits(lo[0]); r[1] = bfbits(lo[1]); r[2] = bfbits(lo[2]); r[3] = bfbits(lo[3]);
    r[4] = bfbits(hi[0]); r[5] = bfbits(hi[1]); r[6] = bfbits(hi[2]); r[7] = bfbits(hi[3]);
    return r;
}

// Pack two f32x4 into one bf16x8 MFMA frag.
__device__ __forceinline__ short8 pack_frag(f32x4 lo, f32x4 hi) {
    short8 r;
    r[0] = bfbits(lo[0]); r[1] = bfbits(lo[1]); r[2] = bfbits(lo[2]); r[3] = bfbits(lo[3]);
    r[4] = bfbits(hi[0]); r[5] = bfbits(hi[1]); r[6] = bfbits(hi[2]); r[7] = bfbits(hi[3]);
    return r;
}

// ---------------------------------------------------------------- k_init ----
__global__ void k_init(int* __restrict__ hist) {
    hist[threadIdx.x] = 0;
}

// ---------------------------------------------------------------- k_hist ----
__global__ __launch_bounds__(256) void k_hist(const int* __restrict__ si,
                                              const int* __restrict__ ti,
                                              int* __restrict__ hist) {
    __shared__ int sh[NPAIR];
    const int t = threadIdx.x;
    sh[t] = 0;
    __syncthreads();
    const int base = blockIdx.x * 1024 + t;
#pragma unroll
    for (int j = 0; j < 4; ++j) {
        const int i = base + j * 256;                       // coalesced
        const int k = (si[i] * NCH + ti[i]) & (NPAIR - 1);  // masked: never OOB
        atomicAdd(&sh[k], 1);
    }
    __syncthreads();
    if (sh[t]) atomicAdd(&hist[t], sh[t]);
}

// ---------------------------------------------------------------- k_scan ----
__global__ __launch_bounds__(256) void k_scan(int* __restrict__ hist,
                                              int* __restrict__ off) {
    __shared__ int s[NPAIR];
    const int t = threadIdx.x;
    const int v = hist[t];
    s[t] = v;
    __syncthreads();
#pragma unroll
    for (int d = 1; d < NPAIR; d <<= 1) {
        const int x = (t >= d) ? s[t - d] : 0;
        __syncthreads();
        s[t] += x;
        __syncthreads();
    }
    off[t + 1] = s[t];                 // inclusive -> off[1..256]
    if (t == 0) off[0] = 0;
    hist[t] = s[t] - v;                // exclusive prefix -> cursor start
}

// ------------------------------------------------------------- k_scatter ----
__global__ __launch_bounds__(256) void k_scatter(const int* __restrict__ si,
                                                 const int* __restrict__ ti,
                                                 int* __restrict__ cursor,
                                                 int* __restrict__ sorted) {
    __shared__ int sh[NPAIR];
    __shared__ int sbase[NPAIR];
    const int t = threadIdx.x;
    sh[t] = 0;
    __syncthreads();
    int key[4], rank[4];
    const int base = blockIdx.x * 1024 + t;
#pragma unroll
    for (int j = 0; j < 4; ++j) {
        const int i = base + j * 256;
        const int k = (si[i] * NCH + ti[i]) & (NPAIR - 1);
        key[j]  = k;
        rank[j] = atomicAdd(&sh[k], 1);
    }
    __syncthreads();
    sbase[t] = sh[t] ? atomicAdd(&cursor[t], sh[t]) : 0;
    __syncthreads();
#pragma unroll
    for (int j = 0; j < 4; ++j) {
        const int slot = sbase[key[j]] + rank[j];
        if (slot >= 0 && slot < NB)
            sorted[slot] = base + j * 256;
    }
}

// ---------------------------------------------------------------- k_gemm ----
// ROUND-4 KERNEL, VERBATIM — the measured optimum (145.4us total; k_gemm
// 42.5us, VGPR 124, no spill). One block per bucket, 512 threads = 8 waves,
// wave-autonomous zero-barrier main loop, 32-row groups: two 16-row halves
// share every B fragment ds_read (8 reads feed 16 MFMAs per k-step), dual
// accumulator chains for ILP, 1-group-ahead register prefetch of the z
// gather. Session-verified DO-NOTs:
//  - r5: 16-row groups / DMA-staged weights / 2 blocks-per-bucket -> 61us
//    (halved per-iteration MFMA exposes the latency chain).
//  - r6: cooperative preprocessing launch -> +30us harness overhead.
//  - r7: weight-first MFMA operand swap (+48 persistent VGPR) -> register
//    cliff at the 124-VGPR budget, scratch spill, 3.5x traffic, 150us.
//  - r1: any >=128-VGPR persistent hoist under min-2-waves bounds spills.
__global__ __launch_bounds__(512, 2)
void k_gemm(const float* __restrict__ z,
            const float* __restrict__ encw,
            const float* __restrict__ decw,
            const float* __restrict__ cpar,
            const float* __restrict__ dpar,
            const int* __restrict__ off,
            const int* __restrict__ sorted,
            float* __restrict__ out) {
    __shared__ int sRowLds[CAP];
    __shared__ __align__(16) __hip_bfloat16 sW1[128 * LDW];
    __shared__ __align__(16) __hip_bfloat16 sW2[128 * LDW];
    __shared__ __align__(16) __hip_bfloat16 sH[8 * 32 * LDH];

    const int bucket = blockIdx.x;
    const int srcc = bucket >> 4;
    const int tgtc = bucket & (NCH - 1);
    const int beg = off[bucket];
    const int end = off[bucket + 1];

    const int tid  = threadIdx.x;
    const int lane = tid & 63;
    const int wv   = tid >> 6;
    const int lr   = lane & 15;
    const int lhi  = lane >> 4;

    {
        const float* W1 = encw + srcc * 16384;
        const float* W2 = decw + tgtc * 16384;
#pragma unroll
        for (int it = 0; it < 4; ++it) {
            const int f = (it * 512 + tid) * 8;
            const int row = f >> 7, col = f & 127;
            *(short8*)(sW1 + row * LDW + col) = cvt_frag(W1 + f);
            *(short8*)(sW2 + row * LDW + col) = cvt_frag(W2 + f);
        }
    }

    float cb[8], db[8];
#pragma unroll
    for (int nt = 0; nt < 8; ++nt) {
        cb[nt] = cpar[srcc * 128 + nt * 16 + lr];
        db[nt] = dpar[tgtc * 128 + nt * 16 + lr];
    }

    __hip_bfloat16* const hs = sH + wv * (32 * LDH);
    f32x4 bufA[8], bufB[8];

    auto pf = [&](int g) {
        const int r0 = sRowLds[(g << 5) + lr];
        const int r1 = sRowLds[(g << 5) + 16 + lr];
        const float* p0 = z + (long)(r0 < 0 ? 0 : r0) * 128 + lhi * 8;
        const float* p1 = z + (long)(r1 < 0 ? 0 : r1) * 128 + lhi * 8;
#pragma unroll
        for (int k = 0; k < 4; ++k) {
            bufA[2 * k]     = *(const f32x4*)(p0 + k * 32);
            bufA[2 * k + 1] = *(const f32x4*)(p0 + k * 32 + 4);
            bufB[2 * k]     = *(const f32x4*)(p1 + k * 32);
            bufB[2 * k + 1] = *(const f32x4*)(p1 + k * 32 + 4);
        }
    };

    for (int cb0 = beg; cb0 < end; cb0 += CAP) {
        const int cnt = min(end - cb0, CAP);
        __syncthreads();
        for (int i = tid; i < CAP; i += 512) {
            int v = (i < cnt) ? sorted[cb0 + i] : -1;
            sRowLds[i] = ((unsigned)v < (unsigned)NB) ? v : -1;
        }
        __syncthreads();

        const int ng = (cnt + 31) >> 5;
        int g = wv;
        if (g < ng) pf(g);
        while (g < ng) {
            short8 a0[4], a1[4];
#pragma unroll
            for (int k = 0; k < 4; ++k) {
                a0[k] = pack_frag(bufA[2 * k], bufA[2 * k + 1]);
                a1[k] = pack_frag(bufB[2 * k], bufB[2 * k + 1]);
            }
            const int gn = g + 8;
            if (gn < ng) pf(gn);

            f32x4 acc0[8], acc1[8];
#pragma unroll
            for (int nt = 0; nt < 8; ++nt) { acc0[nt] = (f32x4)(0.0f); acc1[nt] = (f32x4)(0.0f); }

#pragma unroll
            for (int k = 0; k < 4; ++k) {
#pragma unroll
                for (int nt = 0; nt < 8; ++nt) {
                    const short8 b = *(const short8*)(sW1 + (nt * 16 + lr) * LDW + k * 32 + lhi * 8);
                    acc0[nt] = __builtin_amdgcn_mfma_f32_16x16x32_bf16(a0[k], b, acc0[nt], 0, 0, 0);
                    acc1[nt] = __builtin_amdgcn_mfma_f32_16x16x32_bf16(a1[k], b, acc1[nt], 0, 0, 0);
                }
            }

#pragma unroll
            for (int nt = 0; nt < 8; ++nt)
#pragma unroll
                for (int r = 0; r < 4; ++r) {
                    hs[(lhi * 4 + r) * LDH + nt * 16 + lr]      = __float2bfloat16(acc0[nt][r] + cb[nt]);
                    hs[(16 + lhi * 4 + r) * LDH + nt * 16 + lr] = __float2bfloat16(acc1[nt][r] + cb[nt]);
                }

#pragma unroll
            for (int nt = 0; nt < 8; ++nt) { acc0[nt] = (f32x4)(0.0f); acc1[nt] = (f32x4)(0.0f); }

#pragma unroll
            for (int k = 0; k < 4; ++k) {
                const short8 ah0 = *(const short8*)(hs + lr * LDH + k * 32 + lhi * 8);
                const short8 ah1 = *(const short8*)(hs + (16 + lr) * LDH + k * 32 + lhi * 8);
#pragma unroll
                for (int nt = 0; nt < 8; ++nt) {
                    const short8 b = *(const short8*)(sW2 + (nt * 16 + lr) * LDW + k * 32 + lhi * 8);
                    acc0[nt] = __builtin_amdgcn_mfma_f32_16x16x32_bf16(ah0, b, acc0[nt], 0, 0, 0);
                    acc1[nt] = __builtin_amdgcn_mfma_f32_16x16x32_bf16(ah1, b, acc1[nt], 0, 0, 0);
                }
            }

            {
                int g0[4], g1[4];
#pragma unroll
                for (int r = 0; r < 4; ++r) {
                    g0[r] = sRowLds[(g << 5) + lhi * 4 + r];
                    g1[r] = sRowLds[(g << 5) + 16 + lhi * 4 + r];
                }
#pragma unroll
                for (int nt = 0; nt < 8; ++nt)
#pragma unroll
                    for (int r = 0; r < 4; ++r) {
                        if (g0[r] >= 0)
                            out[(long)g0[r] * 128 + nt * 16 + lr] = acc0[nt][r] + db[nt];
                        if (g1[r] >= 0)
                            out[(long)g1[r] * 128 + nt * 16 + lr] = acc1[nt][r] + db[nt];
                    }
            }
            g = gn;
        }
    }
}

// ------------------------------------------------------------- k_fallback ---
// Zero-workspace correct path: one wave per row, fp32 VALU dot products.
__global__ __launch_bounds__(256)
void k_fallback(const float* __restrict__ z,
                const int* __restrict__ si, const int* __restrict__ ti,
                const float* __restrict__ ew,
                const float* __restrict__ dw,
                const float* __restrict__ cp,
                const float* __restrict__ dp,
                float* __restrict__ out) {
    __shared__ float sh[4][128];
    const int lane = threadIdx.x & 63, wv = threadIdx.x >> 6;
    for (int row = blockIdx.x * 4 + wv; row < NB; row += (int)gridDim.x * 4) {
        const int sc = si[row] & (NCH - 1), tc = ti[row] & (NCH - 1);
        const float* zr = z + (long)row * 128;
        const float* W1 = ew + sc * 16384;
        float h0 = cp[sc * 128 + lane];
        float h1 = cp[sc * 128 + lane + 64];
        for (int d = 0; d < 128; ++d) {
            const float zv = zr[d];
            h0 += zv * W1[lane * 128 + d];
            h1 += zv * W1[(lane + 64) * 128 + d];
        }
        sh[wv][lane] = h0;
        sh[wv][lane + 64] = h1;
        __syncthreads();
        const float* W2 = dw + tc * 16384;
        float o0 = dp[tc * 128 + lane];
        float o1 = dp[tc * 128 + lane + 64];
        for (int r = 0; r < 128; ++r) {
            const float hv = sh[wv][r];
            o0 += hv * W2[lane * 128 + r];
            o1 += hv * W2[(lane + 64) * 128 + r];
        }
        out[(long)row * 128 + lane] = o0;
        out[(long)row * 128 + lane + 64] = o1;
        __syncthreads();
    }
}

// ----------------------------------------------------------------- launch ---
extern "C" void kernel_launch(void* const* d_in, const int* in_sizes, int n_in,
                              void* d_out, int out_size, void* d_ws, size_t ws_size,
                              hipStream_t stream) {
    // Reference dtypes: all float tensors float32, indices int32, output float32.
    const float* z  = (const float*)d_in[0];
    const int*   si = (const int*)d_in[1];
    const int*   ti = (const int*)d_in[2];
    const float* ew = (const float*)d_in[3];
    const float* dw = (const float*)d_in[4];
    const float* cp = (const float*)d_in[5];
    const float* dp = (const float*)d_in[6];
    float* out = (float*)d_out;

    if (ws_size >= (size_t)WS_BYTES) {
        int* hist   = (int*)d_ws + WS_HIST;    // 256, becomes cursor after scan
        int* off    = (int*)d_ws + WS_OFF;     // 257
        int* sorted = (int*)d_ws + WS_SORTED;  // NB

        k_init<<<1, NPAIR, 0, stream>>>(hist);
        k_hist<<<128, 256, 0, stream>>>(si, ti, hist);
        k_scan<<<1, NPAIR, 0, stream>>>(hist, off);
        k_scatter<<<128, 256, 0, stream>>>(si, ti, hist, sorted);
        k_gemm<<<NPAIR, 512, 0, stream>>>(z, ew, dw, cp, dp, off, sorted, out);
    } else {
        k_fallback<<<1024, 256, 0, stream>>>(z, si, ti, ew, dw, cp, dp, out);
    }
}